// Round 1
// baseline (329.159 us; speedup 1.0000x reference)
//
#include <hip/hip_runtime.h>
#include <math.h>

#define MTOT 32768   // BATCH * SEQ_LEN
#define KD 512       // INPUT_DIM
#define HD 512       // HIDDEN_DIM
#define NB 8         // BATCH
#define TS 4096      // SEQ_LEN
#define NCHUNK 64
#define TCHUNK 64

typedef __attribute__((ext_vector_type(8))) short bf16x8;
typedef __attribute__((ext_vector_type(4))) float f32x4;
typedef __attribute__((ext_vector_type(4))) unsigned short us4;

// async 16B global->LDS copy: lane l writes lds_base + l*16
#define GLD16(gsrc, ldst) __builtin_amdgcn_global_load_lds( \
    (const __attribute__((address_space(1))) void*)(gsrc),   \
    (__attribute__((address_space(3))) void*)(ldst), 16, 0, 0)

__device__ __forceinline__ unsigned short f2bf(float f) {
    unsigned u = __float_as_uint(f);
    return (unsigned short)((u + 0x7FFFu + ((u >> 16) & 1u)) >> 16);
}
__device__ __forceinline__ float bf2f(unsigned short u) {
    return __uint_as_float(((unsigned)u) << 16);
}

// ---------------- one cast kernel: x -> x16, {B,G,C,D} -> w16 ----------------
__global__ __launch_bounds__(256) void cast_all(
    const float* __restrict__ x, const float* __restrict__ B,
    const float* __restrict__ G, const float* __restrict__ C,
    const float* __restrict__ D,
    unsigned short* __restrict__ x16, unsigned short* __restrict__ w16)
{
    const int blk = blockIdx.x;
    const float* src;
    unsigned short* dst;
    int i;
    if (blk < (MTOT * KD / 1024)) {
        src = x; dst = x16;
        i = blk * 1024 + threadIdx.x * 4;
    } else {
        const int r = blk - (MTOT * KD / 1024);
        const int mat = r >> 8;                    // 256 blocks per matrix
        src = (mat == 0) ? B : (mat == 1) ? G : (mat == 2) ? C : D;
        dst = w16 + (size_t)mat * (HD * KD);
        i = (r & 255) * 1024 + threadIdx.x * 4;
    }
    float4 v = *(const float4*)(src + i);
    us4 o; o.x = f2bf(v.x); o.y = f2bf(v.y); o.z = f2bf(v.z); o.w = f2bf(v.w);
    *(us4*)(dst + i) = o;
}

// ---------------- fused input GEMMs (B,G) + chunk-local scan ----------------
// A-tile (x) double-buffered in LDS via global_load_lds + counted vmcnt;
// B-operands (B,G rows) read DIRECTLY from global (L2-resident, 1 MiB total).
// block 128(M) x 64(N), BK=64; 4 waves of 64x32; block = 2 chunks exactly.
// grid: x = N-blocks (8), y = M-blocks (256) so consecutive blocks share the
// same x-panel in L2.
__global__ __launch_bounds__(256, 4) void in_gemm_mfma(
    const short* __restrict__ xb, const short* __restrict__ wmat,  // B, G packed
    const float* __restrict__ Avec, const float* __restrict__ bias_h,
    unsigned* __restrict__ ab16, float2* __restrict__ chPS)
{
    __shared__ __align__(16) short Xs[2][128 * 64];
    const int tid = threadIdx.x;
    const int w = tid >> 6, l = tid & 63;
    const int n0 = blockIdx.x * 64;
    const int m0 = blockIdx.y * 128;
    const int wm = (w & 1) * 64;
    const int wn = (w >> 1) * 32;

    int xsrc[4], xdst[4];
    #pragma unroll
    for (int j = 0; j < 4; ++j) {
        const int s = (w * 4 + j) * 64 + l;
        const int r = s >> 3, g = (s & 7) ^ (r & 7);
        xsrc[j] = (m0 + r) * KD + g * 8;
        xdst[j] = (w * 4 + j) * 64 * 8;
    }

    f32x4 acc[2][4][2];
    #pragma unroll
    for (int a = 0; a < 2; ++a)
        #pragma unroll
        for (int i = 0; i < 4; ++i)
            #pragma unroll
            for (int j = 0; j < 2; ++j) acc[a][i][j] = (f32x4)0.0f;

    const int nrow0 = n0 + wn + (l & 15);   // B-fragment row base (per lane)

    // prologue: stage k-tile 0 into buf 0
    #pragma unroll
    for (int j = 0; j < 4; ++j) GLD16(xb + xsrc[j], &Xs[0][xdst[j]]);

    #pragma unroll
    for (int it = 0; it < 8; ++it) {
        const int cur = it & 1;
        const int kk = it * 64;
        // barrier A: everyone done ds_read-ing buf[cur^1] (prev compute)
        asm volatile("s_waitcnt lgkmcnt(0)" ::: "memory");
        __builtin_amdgcn_s_barrier();
        if (it < 7) {
            #pragma unroll
            for (int j = 0; j < 4; ++j)
                GLD16(xb + xsrc[j] + kk + 64, &Xs[cur ^ 1][xdst[j]]);
            // wait own prev-tile loads (oldest); leave the 4 new ones in flight
            asm volatile("s_waitcnt vmcnt(4)" ::: "memory");
        } else {
            asm volatile("s_waitcnt vmcnt(0)" ::: "memory");
        }
        // barrier B: ALL waves' loads into buf[cur] have landed
        __builtin_amdgcn_s_barrier();
        #pragma unroll
        for (int kc = 0; kc < 2; ++kc) {
            const int g = kc * 4 + (l >> 4);
            bf16x8 af[4];
            #pragma unroll
            for (int mt = 0; mt < 4; ++mt) {
                const int r = wm + mt * 16 + (l & 15);
                af[mt] = *(const bf16x8*)(&Xs[cur][r * 64 + ((g ^ (r & 7)) * 8)]);
            }
            #pragma unroll
            for (int mat = 0; mat < 2; ++mat) {
                #pragma unroll
                for (int nt = 0; nt < 2; ++nt) {
                    bf16x8 bfv = *(const bf16x8*)(
                        wmat + (size_t)mat * (HD * KD)
                             + (size_t)(nrow0 + nt * 16) * KD + kk + g * 8);
                    #pragma unroll
                    for (int mt = 0; mt < 4; ++mt)
                        acc[mat][mt][nt] = __builtin_amdgcn_mfma_f32_16x16x32_bf16(
                            af[mt], bfv, acc[mat][mt][nt], 0, 0, 0);
                }
            }
        }
    }

    // epilogue: C/D layout col = l&15, row = (l>>4)*4 + reg
    const int q  = l >> 4;
    const int cl = l & 15;
    const int bidx   = m0 >> 12;
    const int c_in_b = ((m0 & (TS - 1)) >> 6) + (w & 1);
    #pragma unroll
    for (int nt = 0; nt < 2; ++nt) {
        const int n = n0 + wn + nt * 16 + cl;
        const float An1 = 1.0f - Avec[n];
        const float bh  = bias_h[n];
        float Pc = 1.0f, Sc = 0.0f;
        #pragma unroll
        for (int mt = 0; mt < 4; ++mt) {
            float Pl = 1.0f, Sl = 0.0f;
            #pragma unroll
            for (int r = 0; r < 4; ++r) {
                const float vB = acc[0][mt][nt][r];
                const float vG = acc[1][mt][nt][r];
                float g = __builtin_amdgcn_rcpf(1.0f + __expf(-vG));
                g = fminf(fmaxf(g, 0.05f), 0.95f);
                const unsigned short su = f2bf(g * An1);
                const unsigned short bu = f2bf(g * (vB + bh));
                const float a  = 1.0f - bf2f(su);
                const float bb = bf2f(bu);
                const int m = m0 + wm + mt * 16 + q * 4 + r;
                ab16[(size_t)m * HD + n] = (unsigned)su | ((unsigned)bu << 16);
                Sl = fmaf(a, Sl, bb);
                Pl *= a;
            }
            float Pm = 1.0f, Sm = 0.0f;
            #pragma unroll
            for (int k = 0; k < 4; ++k) {
                const float Pk = __shfl(Pl, cl + 16 * k, 64);
                const float Sk = __shfl(Sl, cl + 16 * k, 64);
                Sm = fmaf(Pk, Sm, Sk);
                Pm *= Pk;
            }
            Sc = fmaf(Pm, Sc, Sm);
            Pc *= Pm;
        }
        if (q == 0) {
            chPS[(size_t)c_in_b * (NB * HD) + bidx * HD + n] = make_float2(Pc, Sc);
        }
    }
}

// ---------------- pass3: chain chunk prefix, replay, write hs (bf16) --------
__global__ __launch_bounds__(256) void scan_pass3(
    const unsigned* __restrict__ ab, const float2* __restrict__ chPS,
    unsigned short* __restrict__ hs_out)
{
    const int g = blockIdx.x * blockDim.x + threadIdx.x;
    const int h = g & (HD - 1);
    const int rest = g >> 9;
    const int b = rest & (NB - 1);
    const int c = rest >> 3;          // wave-uniform within a block
    // chain chunks 0..c-1 -> entry state
    const float2* p = chPS + (size_t)b * HD + h;
    float hv = 0.0f;
    for (int j = 0; j < c; ++j) {
        const float2 ps = p[(size_t)j * (NB * HD)];
        hv = fmaf(ps.x, hv, ps.y);
    }
    size_t idx = ((size_t)(b * TS + c * TCHUNK)) * HD + h;
    #pragma unroll 4
    for (int t = 0; t < TCHUNK; ++t) {
        const unsigned v = ab[idx];
        const float a  = 1.0f - bf2f((unsigned short)(v & 0xFFFFu));
        const float bb = bf2f((unsigned short)(v >> 16));
        hv = fmaf(a, hv, bb);
        hs_out[idx] = f2bf(hv);
        idx += HD;
    }
}

// ---------------- dual-A output GEMM: y = (hs@C^T + x@D^T + bias_y)*scale ----
// A-tiles (hs, x) double-buffered in LDS; C/D rows read directly from global
// (L2-resident). block 128x128, BK=64, 4 waves of 64x64.
// grid: x = N-blocks (4), y = M-blocks (256).
__global__ __launch_bounds__(256, 2) void out_gemm_dual(
    const short* __restrict__ hs, const short* __restrict__ xb,
    const short* __restrict__ Cb, const short* __restrict__ Db,
    const float* __restrict__ bias_y, float* __restrict__ y)
{
    __shared__ __align__(16) short Hs[2][128 * 64];
    __shared__ __align__(16) short Xs2[2][128 * 64];
    const int tid = threadIdx.x;
    const int w = tid >> 6, l = tid & 63;
    const int n0 = blockIdx.x * 128;
    const int m0 = blockIdx.y * 128;
    const int wm = (w & 1) * 64;
    const int wn = (w >> 1) * 64;

    int src_m[4], dst_s[4];
    #pragma unroll
    for (int j = 0; j < 4; ++j) {
        const int s = (w * 4 + j) * 64 + l;
        const int r = s >> 3, g = (s & 7) ^ (r & 7);
        src_m[j] = (m0 + r) * HD + g * 8;
        dst_s[j] = (w * 4 + j) * 64 * 8;
    }

    f32x4 acc[4][4];
    #pragma unroll
    for (int i = 0; i < 4; ++i)
        #pragma unroll
        for (int j = 0; j < 4; ++j) acc[i][j] = (f32x4)0.0f;

    const int nrow0 = n0 + wn + (l & 15);

    // prologue: stage k-tile 0 into buf 0
    #pragma unroll
    for (int j = 0; j < 4; ++j) {
        GLD16(hs + src_m[j], &Hs[0][dst_s[j]]);
        GLD16(xb + src_m[j], &Xs2[0][dst_s[j]]);
    }

    #pragma unroll
    for (int it = 0; it < 8; ++it) {
        const int cur = it & 1;
        const int kk = it * 64;
        asm volatile("s_waitcnt lgkmcnt(0)" ::: "memory");
        __builtin_amdgcn_s_barrier();
        if (it < 7) {
            #pragma unroll
            for (int j = 0; j < 4; ++j) {
                GLD16(hs + src_m[j] + kk + 64, &Hs[cur ^ 1][dst_s[j]]);
                GLD16(xb + src_m[j] + kk + 64, &Xs2[cur ^ 1][dst_s[j]]);
            }
            asm volatile("s_waitcnt vmcnt(8)" ::: "memory");
        } else {
            asm volatile("s_waitcnt vmcnt(0)" ::: "memory");
        }
        __builtin_amdgcn_s_barrier();
        #pragma unroll
        for (int kc = 0; kc < 2; ++kc) {
            const int g = kc * 4 + (l >> 4);
            {   // hs @ C^T
                bf16x8 af[4], bfv[4];
                #pragma unroll
                for (int t = 0; t < 4; ++t) {
                    const int ra = wm + t * 16 + (l & 15);
                    af[t] = *(const bf16x8*)(&Hs[cur][ra * 64 + ((g ^ (ra & 7)) * 8)]);
                    bfv[t] = *(const bf16x8*)(
                        Cb + (size_t)(nrow0 + t * 16) * HD + kk + g * 8);
                }
                #pragma unroll
                for (int mt = 0; mt < 4; ++mt)
                    #pragma unroll
                    for (int nt = 0; nt < 4; ++nt)
                        acc[mt][nt] = __builtin_amdgcn_mfma_f32_16x16x32_bf16(
                            af[mt], bfv[nt], acc[mt][nt], 0, 0, 0);
            }
            {   // x @ D^T
                bf16x8 af[4], bfv[4];
                #pragma unroll
                for (int t = 0; t < 4; ++t) {
                    const int ra = wm + t * 16 + (l & 15);
                    af[t] = *(const bf16x8*)(&Xs2[cur][ra * 64 + ((g ^ (ra & 7)) * 8)]);
                    bfv[t] = *(const bf16x8*)(
                        Db + (size_t)(nrow0 + t * 16) * HD + kk + g * 8);
                }
                #pragma unroll
                for (int mt = 0; mt < 4; ++mt)
                    #pragma unroll
                    for (int nt = 0; nt < 4; ++nt)
                        acc[mt][nt] = __builtin_amdgcn_mfma_f32_16x16x32_bf16(
                            af[mt], bfv[nt], acc[mt][nt], 0, 0, 0);
            }
        }
    }

    const float scale = 0.04419417382415922f;  // 1/sqrt(512)
    #pragma unroll
    for (int nt = 0; nt < 4; ++nt) {
        const int n = n0 + wn + nt * 16 + (l & 15);
        const float by = bias_y[n];
        #pragma unroll
        for (int mt = 0; mt < 4; ++mt) {
            #pragma unroll
            for (int r = 0; r < 4; ++r) {
                const int m = m0 + wm + mt * 16 + (l >> 4) * 4 + r;
                y[(size_t)m * HD + n] = (acc[mt][nt][r] + by) * scale;
            }
        }
    }
}

extern "C" void kernel_launch(void* const* d_in, const int* in_sizes, int n_in,
                              void* d_out, int out_size, void* d_ws, size_t ws_size,
                              hipStream_t stream) {
    const float* x      = (const float*)d_in[0];
    const float* Avec   = (const float*)d_in[1];
    const float* Bw     = (const float*)d_in[2];
    const float* Cw     = (const float*)d_in[3];
    const float* Dw     = (const float*)d_in[4];
    const float* Wg     = (const float*)d_in[5];
    const float* bias_h = (const float*)d_in[6];
    const float* bias_y = (const float*)d_in[7];
    float* y = (float*)d_out;

    unsigned* ab16        = (unsigned*)d_ws;                               // 64 MiB
    unsigned short* x16   = (unsigned short*)(ab16 + (size_t)MTOT * HD);   // 32 MiB
    unsigned short* hs16  = x16 + (size_t)MTOT * HD;                       // 32 MiB
    unsigned short* w16   = hs16 + (size_t)MTOT * HD;                      // 2 MiB: B,G,C,D
    float2* chPS = (float2*)(w16 + (size_t)4 * HD * KD);                   // 2 MiB

    cast_all<<<MTOT * KD / 1024 + 4 * (HD * KD / 1024), 256, 0, stream>>>(
        x, Bw, Wg, Cw, Dw, x16, w16);

    in_gemm_mfma<<<dim3(HD / 64, MTOT / 128), 256, 0, stream>>>(
        (const short*)x16, (const short*)w16, Avec, bias_h, ab16, chPS);

    scan_pass3<<<(NB * HD * NCHUNK) / 256, 256, 0, stream>>>(ab16, chPS, hs16);

    out_gemm_dual<<<dim3(HD / 128, MTOT / 128), 256, 0, stream>>>(
        (const short*)hs16, (const short*)x16,
        (const short*)(w16 + (size_t)2 * HD * KD),
        (const short*)(w16 + (size_t)3 * HD * KD), bias_y, y);
}

// Round 2
// 257.735 us; speedup vs baseline: 1.2771x; 1.2771x over previous
//
#include <hip/hip_runtime.h>
#include <math.h>

#define MTOT 32768   // BATCH * SEQ_LEN
#define KD 512       // INPUT_DIM
#define HD 512       // HIDDEN_DIM
#define NB 8         // BATCH
#define TS 4096      // SEQ_LEN
#define NCHUNK 64
#define TCHUNK 64

typedef __attribute__((ext_vector_type(8))) short bf16x8;
typedef __attribute__((ext_vector_type(4))) float f32x4;
typedef __attribute__((ext_vector_type(4))) unsigned short us4;

// async 16B global->LDS copy: lane l writes lds_base + l*16
#define GLD16(gsrc, ldst) __builtin_amdgcn_global_load_lds( \
    (const __attribute__((address_space(1))) void*)(gsrc),   \
    (__attribute__((address_space(3))) void*)(ldst), 16, 0, 0)

__device__ __forceinline__ unsigned short f2bf(float f) {
    unsigned u = __float_as_uint(f);
    return (unsigned short)((u + 0x7FFFu + ((u >> 16) & 1u)) >> 16);
}
__device__ __forceinline__ float bf2f(unsigned short u) {
    return __uint_as_float(((unsigned)u) << 16);
}

// ---------------- one cast kernel: x -> x16, {B,G,C,D} -> w16 ----------------
__global__ __launch_bounds__(256) void cast_all(
    const float* __restrict__ x, const float* __restrict__ B,
    const float* __restrict__ G, const float* __restrict__ C,
    const float* __restrict__ D,
    unsigned short* __restrict__ x16, unsigned short* __restrict__ w16)
{
    const int blk = blockIdx.x;
    const float* src;
    unsigned short* dst;
    int i;
    if (blk < (MTOT * KD / 1024)) {
        src = x; dst = x16;
        i = blk * 1024 + threadIdx.x * 4;
    } else {
        const int r = blk - (MTOT * KD / 1024);
        const int mat = r >> 8;                    // 256 blocks per matrix
        src = (mat == 0) ? B : (mat == 1) ? G : (mat == 2) ? C : D;
        dst = w16 + (size_t)mat * (HD * KD);
        i = (r & 255) * 1024 + threadIdx.x * 4;
    }
    float4 v = *(const float4*)(src + i);
    us4 o; o.x = f2bf(v.x); o.y = f2bf(v.y); o.z = f2bf(v.z); o.w = f2bf(v.w);
    *(us4*)(dst + i) = o;
}

// ---------------- fused input GEMMs (B,G) + chunk-local scan ----------------
// T3 minimum-2-phase: double-buffered LDS (X and W), STAGE(next) issued BEFORE
// compute(cur), single vmcnt(0)+s_barrier per K-tile. Weights via LDS
// (round-1 showed direct-global W is a regression). Grid M-major (x = M).
// block 128(M) x 64(N), BK=64; 4 waves of 64x32; block = 2 chunks exactly.
__global__ __launch_bounds__(256, 2) void in_gemm_mfma(
    const short* __restrict__ xb, const short* __restrict__ wmat,  // B, G packed
    const float* __restrict__ Avec, const float* __restrict__ bias_h,
    unsigned* __restrict__ ab16, float2* __restrict__ chPS)
{
    __shared__ __align__(16) short Xs[2][128 * 64];
    __shared__ __align__(16) short Ws[2][2][64 * 64];
    const int tid = threadIdx.x;
    const int w = tid >> 6, l = tid & 63;
    const int m0 = blockIdx.x * 128;
    const int n0 = blockIdx.y * 64;
    const int wm = (w & 1) * 64;
    const int wn = (w >> 1) * 32;

    int xsrc[4], xdst[4];
    #pragma unroll
    for (int j = 0; j < 4; ++j) {
        const int s = (w * 4 + j) * 64 + l;
        const int r = s >> 3, g = (s & 7) ^ (r & 7);
        xsrc[j] = (m0 + r) * KD + g * 8;
        xdst[j] = (w * 4 + j) * 64 * 8;
    }
    int wsrc[2], wdst[2];
    #pragma unroll
    for (int j = 0; j < 2; ++j) {
        const int s = (w * 2 + j) * 64 + l;
        const int r = s >> 3, g = (s & 7) ^ (r & 7);
        wsrc[j] = (n0 + r) * KD + g * 8;
        wdst[j] = (w * 2 + j) * 64 * 8;
    }

    f32x4 acc[2][4][2];
    #pragma unroll
    for (int a = 0; a < 2; ++a)
        #pragma unroll
        for (int i = 0; i < 4; ++i)
            #pragma unroll
            for (int j = 0; j < 2; ++j) acc[a][i][j] = (f32x4)0.0f;

    // prologue: stage K-tile 0 into buf 0, wait, barrier
    #pragma unroll
    for (int j = 0; j < 4; ++j) GLD16(xb + xsrc[j], &Xs[0][xdst[j]]);
    #pragma unroll
    for (int mat = 0; mat < 2; ++mat)
        #pragma unroll
        for (int j = 0; j < 2; ++j)
            GLD16(wmat + (size_t)mat * (HD * KD) + wsrc[j], &Ws[0][mat][wdst[j]]);
    asm volatile("s_waitcnt vmcnt(0)" ::: "memory");
    __builtin_amdgcn_s_barrier();

    #pragma unroll
    for (int it = 0; it < 8; ++it) {
        const int cur = it & 1;
        const int kk = it * 64;
        if (it < 7) {   // issue next-tile loads FIRST; they fly during compute
            #pragma unroll
            for (int j = 0; j < 4; ++j)
                GLD16(xb + xsrc[j] + kk + 64, &Xs[cur ^ 1][xdst[j]]);
            #pragma unroll
            for (int mat = 0; mat < 2; ++mat)
                #pragma unroll
                for (int j = 0; j < 2; ++j)
                    GLD16(wmat + (size_t)mat * (HD * KD) + wsrc[j] + kk + 64,
                          &Ws[cur ^ 1][mat][wdst[j]]);
        }
        __builtin_amdgcn_s_setprio(1);
        #pragma unroll
        for (int kc = 0; kc < 2; ++kc) {
            const int g = kc * 4 + (l >> 4);
            bf16x8 af[4];
            #pragma unroll
            for (int mt = 0; mt < 4; ++mt) {
                const int r = wm + mt * 16 + (l & 15);
                af[mt] = *(const bf16x8*)(&Xs[cur][r * 64 + ((g ^ (r & 7)) * 8)]);
            }
            #pragma unroll
            for (int mat = 0; mat < 2; ++mat) {
                #pragma unroll
                for (int nt = 0; nt < 2; ++nt) {
                    const int r = wn + nt * 16 + (l & 15);
                    bf16x8 bfv = *(const bf16x8*)(&Ws[cur][mat][r * 64 + ((g ^ (r & 7)) * 8)]);
                    #pragma unroll
                    for (int mt = 0; mt < 4; ++mt)
                        acc[mat][mt][nt] = __builtin_amdgcn_mfma_f32_16x16x32_bf16(
                            af[mt], bfv, acc[mat][mt][nt], 0, 0, 0);
                }
            }
        }
        __builtin_amdgcn_s_setprio(0);
        asm volatile("s_waitcnt vmcnt(0)" ::: "memory");
        __builtin_amdgcn_s_barrier();
    }

    // epilogue: C/D layout col = l&15, row = (l>>4)*4 + reg
    const int q  = l >> 4;
    const int cl = l & 15;
    const int bidx   = m0 >> 12;
    const int c_in_b = ((m0 & (TS - 1)) >> 6) + (w & 1);
    #pragma unroll
    for (int nt = 0; nt < 2; ++nt) {
        const int n = n0 + wn + nt * 16 + cl;
        const float An1 = 1.0f - Avec[n];
        const float bh  = bias_h[n];
        float Pc = 1.0f, Sc = 0.0f;
        #pragma unroll
        for (int mt = 0; mt < 4; ++mt) {
            float Pl = 1.0f, Sl = 0.0f;
            #pragma unroll
            for (int r = 0; r < 4; ++r) {
                const float vB = acc[0][mt][nt][r];
                const float vG = acc[1][mt][nt][r];
                float g = __builtin_amdgcn_rcpf(1.0f + __expf(-vG));
                g = fminf(fmaxf(g, 0.05f), 0.95f);
                const unsigned short su = f2bf(g * An1);
                const unsigned short bu = f2bf(g * (vB + bh));
                const float a  = 1.0f - bf2f(su);
                const float bb = bf2f(bu);
                const int m = m0 + wm + mt * 16 + q * 4 + r;
                ab16[(size_t)m * HD + n] = (unsigned)su | ((unsigned)bu << 16);
                Sl = fmaf(a, Sl, bb);
                Pl *= a;
            }
            float Pm = 1.0f, Sm = 0.0f;
            #pragma unroll
            for (int k = 0; k < 4; ++k) {
                const float Pk = __shfl(Pl, cl + 16 * k, 64);
                const float Sk = __shfl(Sl, cl + 16 * k, 64);
                Sm = fmaf(Pk, Sm, Sk);
                Pm *= Pk;
            }
            Sc = fmaf(Pm, Sc, Sm);
            Pc *= Pm;
        }
        if (q == 0) {
            chPS[(size_t)c_in_b * (NB * HD) + bidx * HD + n] = make_float2(Pc, Sc);
        }
    }
}

// ---------------- pass3: chain chunk prefix, replay, write hs (bf16) --------
__global__ __launch_bounds__(256) void scan_pass3(
    const unsigned* __restrict__ ab, const float2* __restrict__ chPS,
    unsigned short* __restrict__ hs_out)
{
    const int g = blockIdx.x * blockDim.x + threadIdx.x;
    const int h = g & (HD - 1);
    const int rest = g >> 9;
    const int b = rest & (NB - 1);
    const int c = rest >> 3;          // wave-uniform within a block
    // chain chunks 0..c-1 -> entry state
    const float2* p = chPS + (size_t)b * HD + h;
    float hv = 0.0f;
    for (int j = 0; j < c; ++j) {
        const float2 ps = p[(size_t)j * (NB * HD)];
        hv = fmaf(ps.x, hv, ps.y);
    }
    size_t idx = ((size_t)(b * TS + c * TCHUNK)) * HD + h;
    #pragma unroll 4
    for (int t = 0; t < TCHUNK; ++t) {
        const unsigned v = ab[idx];
        const float a  = 1.0f - bf2f((unsigned short)(v & 0xFFFFu));
        const float bb = bf2f((unsigned short)(v >> 16));
        hv = fmaf(a, hv, bb);
        hs_out[idx] = f2bf(hv);
        idx += HD;
    }
}

// ---------------- output GEMM as single K=1024: y = [hs|x] @ [C|D]^T --------
// A' = [hs | x] (M x 1024), W' = [C | D] (512 x 1024), K-concatenated.
// T3 minimum-2-phase double-buffer; 64 KiB LDS total -> 2 blocks/CU.
// block 128x128, BK=64 (16 K-tiles), 4 waves of 64x64. Grid M-major.
__global__ __launch_bounds__(256, 2) void out_gemm_dual(
    const short* __restrict__ hs, const short* __restrict__ xb,
    const short* __restrict__ Cb, const short* __restrict__ Db,
    const float* __restrict__ bias_y, float* __restrict__ y)
{
    __shared__ __align__(16) short As[2][128 * 64];
    __shared__ __align__(16) short Ws[2][128 * 64];
    const int tid = threadIdx.x;
    const int w = tid >> 6, l = tid & 63;
    const int m0 = blockIdx.x * 128;
    const int n0 = blockIdx.y * 128;
    const int wm = (w & 1) * 64;
    const int wn = (w >> 1) * 64;

    // staging: tile row r (0..127), col-group g; source row stride = 512
    int aoff[4], woff[4], dst_s[4];
    #pragma unroll
    for (int j = 0; j < 4; ++j) {
        const int s = (w * 4 + j) * 64 + l;
        const int r = s >> 3, g = (s & 7) ^ (r & 7);
        aoff[j] = (m0 + r) * HD + g * 8;
        woff[j] = (n0 + r) * HD + g * 8;
        dst_s[j] = (w * 4 + j) * 64 * 8;
    }

#define STAGE_OUT(TI, BUF) do {                                         \
    const short* abase_ = (((TI) < 8) ? hs : xb) + ((TI) & 7) * 64;     \
    const short* wbase_ = (((TI) < 8) ? Cb : Db) + ((TI) & 7) * 64;     \
    _Pragma("unroll")                                                   \
    for (int j_ = 0; j_ < 4; ++j_) {                                    \
        GLD16(abase_ + aoff[j_], &As[BUF][dst_s[j_]]);                  \
        GLD16(wbase_ + woff[j_], &Ws[BUF][dst_s[j_]]);                  \
    }                                                                   \
} while (0)

    f32x4 acc[4][4];
    #pragma unroll
    for (int i = 0; i < 4; ++i)
        #pragma unroll
        for (int j = 0; j < 4; ++j) acc[i][j] = (f32x4)0.0f;

    // prologue
    STAGE_OUT(0, 0);
    asm volatile("s_waitcnt vmcnt(0)" ::: "memory");
    __builtin_amdgcn_s_barrier();

    #pragma unroll
    for (int ti = 0; ti < 16; ++ti) {
        const int cur = ti & 1;
        if (ti < 15) STAGE_OUT(ti + 1, cur ^ 1);
        __builtin_amdgcn_s_setprio(1);
        #pragma unroll
        for (int kc = 0; kc < 2; ++kc) {
            const int g = kc * 4 + (l >> 4);
            bf16x8 af[4], bfv[4];
            #pragma unroll
            for (int t = 0; t < 4; ++t) {
                const int ra = wm + t * 16 + (l & 15);
                af[t] = *(const bf16x8*)(&As[cur][ra * 64 + ((g ^ (ra & 7)) * 8)]);
                const int rb = wn + t * 16 + (l & 15);
                bfv[t] = *(const bf16x8*)(&Ws[cur][rb * 64 + ((g ^ (rb & 7)) * 8)]);
            }
            #pragma unroll
            for (int mt = 0; mt < 4; ++mt)
                #pragma unroll
                for (int nt = 0; nt < 4; ++nt)
                    acc[mt][nt] = __builtin_amdgcn_mfma_f32_16x16x32_bf16(
                        af[mt], bfv[nt], acc[mt][nt], 0, 0, 0);
        }
        __builtin_amdgcn_s_setprio(0);
        asm volatile("s_waitcnt vmcnt(0)" ::: "memory");
        __builtin_amdgcn_s_barrier();
    }
#undef STAGE_OUT

    const float scale = 0.04419417382415922f;  // 1/sqrt(512)
    #pragma unroll
    for (int nt = 0; nt < 4; ++nt) {
        const int n = n0 + wn + nt * 16 + (l & 15);
        const float by = bias_y[n];
        #pragma unroll
        for (int mt = 0; mt < 4; ++mt) {
            #pragma unroll
            for (int r = 0; r < 4; ++r) {
                const int m = m0 + wm + mt * 16 + (l >> 4) * 4 + r;
                y[(size_t)m * HD + n] = (acc[mt][nt][r] + by) * scale;
            }
        }
    }
}

extern "C" void kernel_launch(void* const* d_in, const int* in_sizes, int n_in,
                              void* d_out, int out_size, void* d_ws, size_t ws_size,
                              hipStream_t stream) {
    const float* x      = (const float*)d_in[0];
    const float* Avec   = (const float*)d_in[1];
    const float* Bw     = (const float*)d_in[2];
    const float* Cw     = (const float*)d_in[3];
    const float* Dw     = (const float*)d_in[4];
    const float* Wg     = (const float*)d_in[5];
    const float* bias_h = (const float*)d_in[6];
    const float* bias_y = (const float*)d_in[7];
    float* y = (float*)d_out;

    unsigned* ab16        = (unsigned*)d_ws;                               // 64 MiB
    unsigned short* x16   = (unsigned short*)(ab16 + (size_t)MTOT * HD);   // 32 MiB
    unsigned short* hs16  = x16 + (size_t)MTOT * HD;                       // 32 MiB
    unsigned short* w16   = hs16 + (size_t)MTOT * HD;                      // 2 MiB: B,G,C,D
    float2* chPS = (float2*)(w16 + (size_t)4 * HD * KD);                   // 2 MiB

    cast_all<<<MTOT * KD / 1024 + 4 * (HD * KD / 1024), 256, 0, stream>>>(
        x, Bw, Wg, Cw, Dw, x16, w16);

    in_gemm_mfma<<<dim3(MTOT / 128, HD / 64), 256, 0, stream>>>(
        (const short*)x16, (const short*)w16, Avec, bias_h, ab16, chPS);

    scan_pass3<<<(NB * HD * NCHUNK) / 256, 256, 0, stream>>>(ab16, chPS, hs16);

    out_gemm_dual<<<dim3(MTOT / 128, HD / 128), 256, 0, stream>>>(
        (const short*)hs16, (const short*)x16,
        (const short*)(w16 + (size_t)2 * HD * KD),
        (const short*)(w16 + (size_t)3 * HD * KD), bias_y, y);
}

// Round 3
// 249.730 us; speedup vs baseline: 1.3181x; 1.0321x over previous
//
#include <hip/hip_runtime.h>
#include <math.h>

#define MTOT 32768   // BATCH * SEQ_LEN
#define KD 512       // INPUT_DIM
#define HD 512       // HIDDEN_DIM
#define NB 8         // BATCH
#define TS 4096      // SEQ_LEN
#define NCHUNK 64
#define TCHUNK 64

typedef __attribute__((ext_vector_type(8))) short bf16x8;
typedef __attribute__((ext_vector_type(4))) float f32x4;
typedef __attribute__((ext_vector_type(4))) unsigned short us4;

// async 16B global->LDS copy: lane l writes lds_base + l*16
#define GLD16(gsrc, ldst) __builtin_amdgcn_global_load_lds( \
    (const __attribute__((address_space(1))) void*)(gsrc),   \
    (__attribute__((address_space(3))) void*)(ldst), 16, 0, 0)

__device__ __forceinline__ unsigned short f2bf(float f) {
    unsigned u = __float_as_uint(f);
    return (unsigned short)((u + 0x7FFFu + ((u >> 16) & 1u)) >> 16);
}
__device__ __forceinline__ float bf2f(unsigned short u) {
    return __uint_as_float(((unsigned)u) << 16);
}

// ---------------- one cast kernel: x -> x16, {B,G,C,D} -> w16 ----------------
__global__ __launch_bounds__(256) void cast_all(
    const float* __restrict__ x, const float* __restrict__ B,
    const float* __restrict__ G, const float* __restrict__ C,
    const float* __restrict__ D,
    unsigned short* __restrict__ x16, unsigned short* __restrict__ w16)
{
    const int blk = blockIdx.x;
    const float* src;
    unsigned short* dst;
    int i;
    if (blk < (MTOT * KD / 1024)) {
        src = x; dst = x16;
        i = blk * 1024 + threadIdx.x * 4;
    } else {
        const int r = blk - (MTOT * KD / 1024);
        const int mat = r >> 8;                    // 256 blocks per matrix
        src = (mat == 0) ? B : (mat == 1) ? G : (mat == 2) ? C : D;
        dst = w16 + (size_t)mat * (HD * KD);
        i = (r & 255) * 1024 + threadIdx.x * 4;
    }
    float4 v = *(const float4*)(src + i);
    us4 o; o.x = f2bf(v.x); o.y = f2bf(v.y); o.z = f2bf(v.z); o.w = f2bf(v.w);
    *(us4*)(dst + i) = o;
}

// ---------------- fused input GEMMs (B,G) + chunk-local scan ----------------
// Counted-vmcnt 2-deep pipeline: tile t issued at end of iter t-2, waited with
// vmcnt(8) at top of iter t (8 newer loads stay in flight across barriers).
// XCD swizzle: xcd = bid&7 owns contiguous M-range x all 8 N-blocks -> x-panel
// reuse is L2-local (round-1's inverted mapping tripled FETCH).
// block 128(M) x 64(N), BK=64; 4 waves of 64x32; block = 2 chunks exactly.
__global__ __launch_bounds__(256, 2) void in_gemm_mfma(
    const short* __restrict__ xb, const short* __restrict__ wmat,  // B, G packed
    const float* __restrict__ Avec, const float* __restrict__ bias_h,
    unsigned* __restrict__ ab16, float2* __restrict__ chPS)
{
    __shared__ __align__(16) short Xs[2][128 * 64];
    __shared__ __align__(16) short Ws[2][2][64 * 64];
    const int tid = threadIdx.x;
    const int w = tid >> 6, l = tid & 63;
    // bijective XCD decode: 2048 blocks, 8 XCDs, 32 M-panels x 8 N each
    const int bid = blockIdx.x;
    const int xcd = bid & 7;
    const int jj  = bid >> 3;               // 0..255
    const int n0  = (jj & 7) * 64;
    const int m0  = (xcd * 32 + (jj >> 3)) * 128;
    const int wm = (w & 1) * 64;
    const int wn = (w >> 1) * 32;

    int xsrc[4], xdst[4];
    #pragma unroll
    for (int j = 0; j < 4; ++j) {
        const int s = (w * 4 + j) * 64 + l;
        const int r = s >> 3, g = (s & 7) ^ (r & 7);
        xsrc[j] = (m0 + r) * KD + g * 8;
        xdst[j] = (w * 4 + j) * 64 * 8;
    }
    int wsrc[2], wdst[2];
    #pragma unroll
    for (int j = 0; j < 2; ++j) {
        const int s = (w * 2 + j) * 64 + l;
        const int r = s >> 3, g = (s & 7) ^ (r & 7);
        wsrc[j] = (n0 + r) * KD + g * 8;
        wdst[j] = (w * 2 + j) * 64 * 8;
    }

#define STAGE_IN(TI, BUF) do {                                              \
    const int kk_ = (TI) * 64;                                              \
    _Pragma("unroll")                                                       \
    for (int j_ = 0; j_ < 4; ++j_)                                          \
        GLD16(xb + xsrc[j_] + kk_, &Xs[BUF][xdst[j_]]);                     \
    _Pragma("unroll")                                                       \
    for (int m_ = 0; m_ < 2; ++m_)                                          \
        _Pragma("unroll")                                                   \
        for (int j_ = 0; j_ < 2; ++j_)                                      \
            GLD16(wmat + (size_t)m_ * (HD * KD) + wsrc[j_] + kk_,           \
                  &Ws[BUF][m_][wdst[j_]]);                                  \
} while (0)

    f32x4 acc[2][4][2];
    #pragma unroll
    for (int a = 0; a < 2; ++a)
        #pragma unroll
        for (int i = 0; i < 4; ++i)
            #pragma unroll
            for (int j = 0; j < 2; ++j) acc[a][i][j] = (f32x4)0.0f;

    // prologue: two tiles in flight (16 outstanding loads)
    STAGE_IN(0, 0);
    STAGE_IN(1, 1);

    #pragma unroll
    for (int it = 0; it < 8; ++it) {
        const int cur = it & 1;
        if (it < 7) asm volatile("s_waitcnt vmcnt(8)" ::: "memory");
        else        asm volatile("s_waitcnt vmcnt(0)" ::: "memory");
        __builtin_amdgcn_s_barrier();      // buf[cur] fully landed, all waves
        __builtin_amdgcn_s_setprio(1);
        #pragma unroll
        for (int kc = 0; kc < 2; ++kc) {
            const int g = kc * 4 + (l >> 4);
            bf16x8 af[4];
            #pragma unroll
            for (int mt = 0; mt < 4; ++mt) {
                const int r = wm + mt * 16 + (l & 15);
                af[mt] = *(const bf16x8*)(&Xs[cur][r * 64 + ((g ^ (r & 7)) * 8)]);
            }
            #pragma unroll
            for (int mat = 0; mat < 2; ++mat) {
                #pragma unroll
                for (int nt = 0; nt < 2; ++nt) {
                    const int r = wn + nt * 16 + (l & 15);
                    bf16x8 bfv = *(const bf16x8*)(&Ws[cur][mat][r * 64 + ((g ^ (r & 7)) * 8)]);
                    #pragma unroll
                    for (int mt = 0; mt < 4; ++mt)
                        acc[mat][mt][nt] = __builtin_amdgcn_mfma_f32_16x16x32_bf16(
                            af[mt], bfv, acc[mat][mt][nt], 0, 0, 0);
                }
            }
        }
        __builtin_amdgcn_s_setprio(0);
        asm volatile("s_waitcnt lgkmcnt(0)" ::: "memory");
        __builtin_amdgcn_s_barrier();      // all waves done reading buf[cur]
        if (it < 6) STAGE_IN(it + 2, cur); // overwrite buf[cur] for tile it+2
    }
#undef STAGE_IN

    // epilogue: C/D layout col = l&15, row = (l>>4)*4 + reg
    const int q  = l >> 4;
    const int cl = l & 15;
    const int bidx   = m0 >> 12;
    const int c_in_b = ((m0 & (TS - 1)) >> 6) + (w & 1);
    #pragma unroll
    for (int nt = 0; nt < 2; ++nt) {
        const int n = n0 + wn + nt * 16 + cl;
        const float An1 = 1.0f - Avec[n];
        const float bh  = bias_h[n];
        float Pc = 1.0f, Sc = 0.0f;
        #pragma unroll
        for (int mt = 0; mt < 4; ++mt) {
            float Pl = 1.0f, Sl = 0.0f;
            #pragma unroll
            for (int r = 0; r < 4; ++r) {
                const float vB = acc[0][mt][nt][r];
                const float vG = acc[1][mt][nt][r];
                float g = __builtin_amdgcn_rcpf(1.0f + __expf(-vG));
                g = fminf(fmaxf(g, 0.05f), 0.95f);
                const unsigned short su = f2bf(g * An1);
                const unsigned short bu = f2bf(g * (vB + bh));
                const float a  = 1.0f - bf2f(su);
                const float bb = bf2f(bu);
                const int m = m0 + wm + mt * 16 + q * 4 + r;
                ab16[(size_t)m * HD + n] = (unsigned)su | ((unsigned)bu << 16);
                Sl = fmaf(a, Sl, bb);
                Pl *= a;
            }
            float Pm = 1.0f, Sm = 0.0f;
            #pragma unroll
            for (int k = 0; k < 4; ++k) {
                const float Pk = __shfl(Pl, cl + 16 * k, 64);
                const float Sk = __shfl(Sl, cl + 16 * k, 64);
                Sm = fmaf(Pk, Sm, Sk);
                Pm *= Pk;
            }
            Sc = fmaf(Pm, Sc, Sm);
            Pc *= Pm;
        }
        if (q == 0) {
            chPS[(size_t)c_in_b * (NB * HD) + bidx * HD + n] = make_float2(Pc, Sc);
        }
    }
}

// ---------------- pass3: chain chunk prefix, replay, write hs (bf16) --------
// 4 h-values per thread: uint4 loads (16B/lane), us4 stores (8B/lane).
__global__ __launch_bounds__(256) void scan_pass3(
    const unsigned* __restrict__ ab, const float2* __restrict__ chPS,
    unsigned short* __restrict__ hs_out)
{
    const int g = blockIdx.x * blockDim.x + threadIdx.x;   // 65536 threads
    const int h4 = (g & 127) * 4;
    const int rest = g >> 7;
    const int b = rest & (NB - 1);
    const int c = rest >> 3;          // wave-uniform within a block
    // chain chunks 0..c-1 -> entry state (4 lanes of h at once)
    const float2* p = chPS + (size_t)b * HD + h4;
    float hv0 = 0.0f, hv1 = 0.0f, hv2 = 0.0f, hv3 = 0.0f;
    for (int jc = 0; jc < c; ++jc) {
        const float4 ps01 = *(const float4*)(p + (size_t)jc * (NB * HD));
        const float4 ps23 = *(const float4*)(p + (size_t)jc * (NB * HD) + 2);
        hv0 = fmaf(ps01.x, hv0, ps01.y);
        hv1 = fmaf(ps01.z, hv1, ps01.w);
        hv2 = fmaf(ps23.x, hv2, ps23.y);
        hv3 = fmaf(ps23.z, hv3, ps23.w);
    }
    size_t idx = ((size_t)(b * TS + c * TCHUNK)) * HD + h4;
    #pragma unroll 4
    for (int t = 0; t < TCHUNK; ++t) {
        const uint4 v = *(const uint4*)(ab + idx);
        const float a0 = 1.0f - bf2f((unsigned short)(v.x & 0xFFFFu));
        const float a1 = 1.0f - bf2f((unsigned short)(v.y & 0xFFFFu));
        const float a2 = 1.0f - bf2f((unsigned short)(v.z & 0xFFFFu));
        const float a3 = 1.0f - bf2f((unsigned short)(v.w & 0xFFFFu));
        hv0 = fmaf(a0, hv0, bf2f((unsigned short)(v.x >> 16)));
        hv1 = fmaf(a1, hv1, bf2f((unsigned short)(v.y >> 16)));
        hv2 = fmaf(a2, hv2, bf2f((unsigned short)(v.z >> 16)));
        hv3 = fmaf(a3, hv3, bf2f((unsigned short)(v.w >> 16)));
        us4 o; o.x = f2bf(hv0); o.y = f2bf(hv1); o.z = f2bf(hv2); o.w = f2bf(hv3);
        *(us4*)(hs_out + idx) = o;
        idx += HD;
    }
}

// ---------------- output GEMM as single K=1024: y = [hs|x] @ [C|D]^T --------
// Counted-vmcnt 2-deep pipeline, same as in_gemm. 16 K-tiles.
// XCD swizzle: 1024 blocks, 8 XCDs, 32 M-panels x 4 N each.
__global__ __launch_bounds__(256, 2) void out_gemm_dual(
    const short* __restrict__ hs, const short* __restrict__ xb,
    const short* __restrict__ Cb, const short* __restrict__ Db,
    const float* __restrict__ bias_y, float* __restrict__ y)
{
    __shared__ __align__(16) short As[2][128 * 64];
    __shared__ __align__(16) short Ws[2][128 * 64];
    const int tid = threadIdx.x;
    const int w = tid >> 6, l = tid & 63;
    const int bid = blockIdx.x;
    const int xcd = bid & 7;
    const int jj  = bid >> 3;               // 0..127
    const int n0  = (jj & 3) * 128;
    const int m0  = (xcd * 32 + (jj >> 2)) * 128;
    const int wm = (w & 1) * 64;
    const int wn = (w >> 1) * 64;

    int aoff[4], woff[4], dst_s[4];
    #pragma unroll
    for (int j = 0; j < 4; ++j) {
        const int s = (w * 4 + j) * 64 + l;
        const int r = s >> 3, g = (s & 7) ^ (r & 7);
        aoff[j] = (m0 + r) * HD + g * 8;
        woff[j] = (n0 + r) * HD + g * 8;
        dst_s[j] = (w * 4 + j) * 64 * 8;
    }

#define STAGE_OUT(TI, BUF) do {                                         \
    const short* abase_ = (((TI) < 8) ? hs : xb) + ((TI) & 7) * 64;     \
    const short* wbase_ = (((TI) < 8) ? Cb : Db) + ((TI) & 7) * 64;     \
    _Pragma("unroll")                                                   \
    for (int j_ = 0; j_ < 4; ++j_) {                                    \
        GLD16(abase_ + aoff[j_], &As[BUF][dst_s[j_]]);                  \
        GLD16(wbase_ + woff[j_], &Ws[BUF][dst_s[j_]]);                  \
    }                                                                   \
} while (0)

    f32x4 acc[4][4];
    #pragma unroll
    for (int i = 0; i < 4; ++i)
        #pragma unroll
        for (int j = 0; j < 4; ++j) acc[i][j] = (f32x4)0.0f;

    // prologue: two tiles in flight
    STAGE_OUT(0, 0);
    STAGE_OUT(1, 1);

    #pragma unroll
    for (int ti = 0; ti < 16; ++ti) {
        const int cur = ti & 1;
        if (ti < 15) asm volatile("s_waitcnt vmcnt(8)" ::: "memory");
        else         asm volatile("s_waitcnt vmcnt(0)" ::: "memory");
        __builtin_amdgcn_s_barrier();
        __builtin_amdgcn_s_setprio(1);
        #pragma unroll
        for (int kc = 0; kc < 2; ++kc) {
            const int g = kc * 4 + (l >> 4);
            bf16x8 af[4], bfv[4];
            #pragma unroll
            for (int t = 0; t < 4; ++t) {
                const int ra = wm + t * 16 + (l & 15);
                af[t] = *(const bf16x8*)(&As[cur][ra * 64 + ((g ^ (ra & 7)) * 8)]);
                const int rb = wn + t * 16 + (l & 15);
                bfv[t] = *(const bf16x8*)(&Ws[cur][rb * 64 + ((g ^ (rb & 7)) * 8)]);
            }
            #pragma unroll
            for (int mt = 0; mt < 4; ++mt)
                #pragma unroll
                for (int nt = 0; nt < 4; ++nt)
                    acc[mt][nt] = __builtin_amdgcn_mfma_f32_16x16x32_bf16(
                        af[mt], bfv[nt], acc[mt][nt], 0, 0, 0);
        }
        __builtin_amdgcn_s_setprio(0);
        asm volatile("s_waitcnt lgkmcnt(0)" ::: "memory");
        __builtin_amdgcn_s_barrier();
        if (ti < 14) STAGE_OUT(ti + 2, cur);
    }
#undef STAGE_OUT

    const float scale = 0.04419417382415922f;  // 1/sqrt(512)
    #pragma unroll
    for (int nt = 0; nt < 4; ++nt) {
        const int n = n0 + wn + nt * 16 + (l & 15);
        const float by = bias_y[n];
        #pragma unroll
        for (int mt = 0; mt < 4; ++mt) {
            #pragma unroll
            for (int r = 0; r < 4; ++r) {
                const int m = m0 + wm + mt * 16 + (l >> 4) * 4 + r;
                y[(size_t)m * HD + n] = (acc[mt][nt][r] + by) * scale;
            }
        }
    }
}

extern "C" void kernel_launch(void* const* d_in, const int* in_sizes, int n_in,
                              void* d_out, int out_size, void* d_ws, size_t ws_size,
                              hipStream_t stream) {
    const float* x      = (const float*)d_in[0];
    const float* Avec   = (const float*)d_in[1];
    const float* Bw     = (const float*)d_in[2];
    const float* Cw     = (const float*)d_in[3];
    const float* Dw     = (const float*)d_in[4];
    const float* Wg     = (const float*)d_in[5];
    const float* bias_h = (const float*)d_in[6];
    const float* bias_y = (const float*)d_in[7];
    float* y = (float*)d_out;

    unsigned* ab16        = (unsigned*)d_ws;                               // 64 MiB
    unsigned short* x16   = (unsigned short*)(ab16 + (size_t)MTOT * HD);   // 32 MiB
    unsigned short* hs16  = x16 + (size_t)MTOT * HD;                       // 32 MiB
    unsigned short* w16   = hs16 + (size_t)MTOT * HD;                      // 2 MiB: B,G,C,D
    float2* chPS = (float2*)(w16 + (size_t)4 * HD * KD);                   // 2 MiB

    cast_all<<<MTOT * KD / 1024 + 4 * (HD * KD / 1024), 256, 0, stream>>>(
        x, Bw, Wg, Cw, Dw, x16, w16);

    in_gemm_mfma<<<2048, 256, 0, stream>>>(
        (const short*)x16, (const short*)w16, Avec, bias_h, ab16, chPS);

    scan_pass3<<<(NB * HD * NCHUNK / 4) / 256, 256, 0, stream>>>(ab16, chPS, hs16);

    out_gemm_dual<<<1024, 256, 0, stream>>>(
        (const short*)hs16, (const short*)x16,
        (const short*)(w16 + (size_t)2 * HD * KD),
        (const short*)(w16 + (size_t)3 * HD * KD), bias_y, y);
}